// Round 14
// baseline (366.288 us; speedup 1.0000x reference)
//
#include <hip/hip_runtime.h>

typedef unsigned int u32;
typedef unsigned long long u64;
typedef unsigned short ushort_t;

#define NROWS 32768
#define KENT  8192
#define DDIM  256
#define ND_TOTAL 8388608
#define CAP   1048576u
#define LBUF  1536

// ---- workspace layout (bytes) ----
#define WS_COUNTER   0
#define WS_A         64
#define WS_MARG      131136
#define WS_ROWTHR    262208
#define WS_KEYS      393280
#define WS_CANDS     655424
#define WS_ZH        9044032
#define WS_EH        25821248
#define WS_LOSS      30015552
#define WS_NEEDED    30019648ull

typedef __attribute__((ext_vector_type(8))) short s16x8;
typedef __attribute__((ext_vector_type(4))) float f32x4;

__device__ __forceinline__ unsigned short bf16_rne(float f) {
  u32 u = __float_as_uint(f);
  u32 r = (u + 0x7fffu + ((u >> 16) & 1u)) >> 16;
  return (unsigned short)r;
}

// monotone float<->u32 key; smaller float => smaller key
__device__ __forceinline__ u32 fkey(float s) {
  u32 b = __float_as_uint(s);
  u32 mask = (u32)((int)b >> 31);
  return b ^ (mask | 0x80000000u);
}
__device__ __forceinline__ float unkey(u32 k) {
  u32 b = (k & 0x80000000u) ? (k ^ 0x80000000u) : ~k;
  return __uint_as_float(b);
}
#define KEY_INF 0xFF800000u   // fkey(+inf); NOT 0xFFFFFFFF (that's NaN)

// async global->LDS: 16B/lane, LDS dest = wave-uniform base + lane*16
__device__ __forceinline__ void gll16(const void* g, void* l) {
  __builtin_amdgcn_global_load_lds((const __attribute__((address_space(1))) void*)g,
                                   (__attribute__((address_space(3))) void*)l, 16, 0, 0);
}

// ---------------- prep: z -> bf16, A, margin, init keys ----------------
__global__ __launch_bounds__(256) void vq_prep_z(
    const float* __restrict__ z, unsigned short* __restrict__ zh,
    float* __restrict__ A, float* __restrict__ marg, u64* __restrict__ keys) {
  const int wid = threadIdx.x >> 6, lane = threadIdx.x & 63;
  const int row = blockIdx.x * 4 + wid;
  float4 v = ((const float4*)z)[(size_t)row * 64 + lane];
  ushort4 h;
  h.x = bf16_rne(v.x); h.y = bf16_rne(v.y); h.z = bf16_rne(v.z); h.w = bf16_rne(v.w);
  *(ushort4*)&zh[(size_t)row * 256 + lane * 4] = h;
  double s  = (double)v.x * v.x + (double)v.y * v.y + (double)v.z * v.z + (double)v.w * v.w;
  double s1 = fabs((double)v.x) + fabs((double)v.y) + fabs((double)v.z) + fabs((double)v.w);
#pragma unroll
  for (int m = 1; m <= 32; m <<= 1) { s += __shfl_xor(s, m, 64); s1 += __shfl_xor(s1, m, 64); }
  if (lane == 0) {
    float Af = (float)s;
    u32 bits = __float_as_uint(Af);
    float ulpA = __uint_as_float((bits & 0x7f800000u) - (23u << 23));  // A >= 128 always
    A[row] = Af;
    // marg >= 2*ulpA + 2*E_dot (bf16-conversion bound); proven rounds 3-13
    marg[row] = 4.0f * ulpA + 3.86e-6f * (float)s1 + 4e-6f;
    keys[row] = ~0ull;
  }
}

// ---------------- prep: codebook -> bf16, zero counter ----------------
__global__ __launch_bounds__(256) void vq_prep_e(
    const float* __restrict__ cb, unsigned short* __restrict__ eh,
    u32* __restrict__ counter) {
  if (blockIdx.x == 0 && threadIdx.x == 0) *counter = 0u;
  const int wid = threadIdx.x >> 6, lane = threadIdx.x & 63;
  const int row = blockIdx.x * 4 + wid;
  float4 v = ((const float4*)cb)[(size_t)row * 64 + lane];
  ushort4 h;
  h.x = bf16_rne(v.x); h.y = bf16_rne(v.y); h.z = bf16_rne(v.z); h.w = bf16_rne(v.w);
  *(ushort4*)&eh[(size_t)row * 256 + lane * 4] = h;
}

// ---------------- fused single-sweep GEMM + in-block exact resolution ----------------
// r13's fi=4 x fj=4 structure (0.5 LDS reads/MFMA, best measured ratio) RESIZED
// for 2 blocks/CU (r9/r10 evidence: cross-block decoupling is the binding
// constraint, not LDS bandwidth). 512 blocks x 64 rows, 256 thr = 4 waves
// (1 row-group x 4 col-groups), wave = 64r x 64c. A staged ONCE into 8
// swizzled sub-buffers (32KB resident); B double-buffered 2x16KB (proven
// formulas), 264 K=32 stages, plain __syncthreads. LDS ~78.6KB -> 2 blocks/CU.
// Tile order [0,1..31,0] (tile-0 warmup, emission at it=32). Candidates ->
// LDS buffer, resolved in-block (bit-faithful sequential fmaf f32); global
// list = overflow backstop.
__global__ __launch_bounds__(256, 2) void vq_fused10(
    const ushort_t* __restrict__ zh, const ushort_t* __restrict__ eh,
    const float* __restrict__ z, const float* __restrict__ cb,
    const float* __restrict__ Ag, const float* __restrict__ marg,
    float* __restrict__ rowthr, u64* __restrict__ keys,
    u64* __restrict__ cands, u32* __restrict__ counter) {
  __shared__ __align__(16) ushort_t Asm[8][2048];   // 8 kt sub-buffers x 4KB = 32KB (resident)
  __shared__ __align__(16) ushort_t Bsm[2][8192];   // 2 x 16KB (256 entries x 32 dims)
  __shared__ u32 rowKey[64];
  __shared__ float mgS[64];
  __shared__ u64 lbuf[LBUF];                        // 12KB
  __shared__ u32 lcount;
  __shared__ float thrF[64];

  const int tid = threadIdx.x, w = tid >> 6, lane = tid & 63;
  const int l15 = lane & 15, l4 = lane >> 4;
  const int wcol = w * 64;                          // 4 col-groups; all waves own all 64 rows
  const int rowbase = blockIdx.x * 64;

  if (tid < 64) {
    rowKey[tid] = KEY_INF;
    mgS[tid] = marg[rowbase + tid];
  }
  if (tid == 0) lcount = 0u;

  // ---- stage A into LDS: wave w fills sub-buffers kt=w and kt=w+4
  // (dims kt*32..kt*32+32). Sub-buffer layout (proven): slot t in [0,256):
  // row e=t>>2, stored chunk c=t&3 holds global dim-chunk c^((e>>1)&3).
#pragma unroll
  for (int sb = 0; sb < 2; ++sb) {
    const int ktg = w + sb * 4;
#pragma unroll
    for (int i = 0; i < 4; ++i) {
      const int t = i * 64 + lane;
      const int e = t >> 2;
      const int gc = (t & 3) ^ ((e >> 1) & 3);
      gll16(zh + (size_t)(rowbase + e) * 256 + ktg * 32 + gc * 8, &Asm[ktg][i * 512]);
    }
  }

  // ---- B staging (proven formulas): slot t in [0,1024): entry e=t>>2,
  // stored chunk c=t&3 holds global chunk c^((e>>1)&3). 4 waves x 4 slots/lane.
  const ushort_t *gs0, *gs1, *gs2, *gs3;
  {
    int t, e;
    t = w * 256 + lane;       e = t >> 2; gs0 = eh + (size_t)e * 256 + (((t & 3) ^ ((e >> 1) & 3)) * 8);
    t = w * 256 + lane + 64;  e = t >> 2; gs1 = eh + (size_t)e * 256 + (((t & 3) ^ ((e >> 1) & 3)) * 8);
    t = w * 256 + lane + 128; e = t >> 2; gs2 = eh + (size_t)e * 256 + (((t & 3) ^ ((e >> 1) & 3)) * 8);
    t = w * 256 + lane + 192; e = t >> 2; gs3 = eh + (size_t)e * 256 + (((t & 3) ^ ((e >> 1) & 3)) * 8);
  }

#define ISSUE(BUF, CT, KT) do {                                        \
    size_t o_ = (size_t)(CT) * 65536 + (size_t)(KT) * 32;              \
    gll16(gs0 + o_, &Bsm[(BUF)][w * 2048]);                            \
    gll16(gs1 + o_, &Bsm[(BUF)][w * 2048 + 512]);                      \
    gll16(gs2 + o_, &Bsm[(BUF)][w * 2048 + 1024]);                     \
    gll16(gs3 + o_, &Bsm[(BUF)][w * 2048 + 1536]);                     \
  } while (0)

  // swizzled read offsets (ushort index within a sub-buffer / B buffer)
  int aoff[4], boff[4];
#pragma unroll
  for (int f = 0; f < 4; ++f) {
    int ea = f * 16 + l15;
    aoff[f] = ea * 32 + (l4 ^ ((ea >> 1) & 3)) * 8;
    int eb = wcol + f * 16 + l15;
    boff[f] = eb * 32 + (l4 ^ ((eb >> 1) & 3)) * 8;
  }

  ISSUE(0, 0, 0);
  __syncthreads();                       // drains A + B0 + covers LDS init
  int cur = 0;

#pragma unroll 1
  for (int it = 0; it <= 32; ++it) {
    const int ct = (it < 32) ? it : 0;   // tile 0: warmup at it=0, emission at it=32
    f32x4 acc[4][4];
#pragma unroll
    for (int fi = 0; fi < 4; ++fi)
#pragma unroll
      for (int fj = 0; fj < 4; ++fj) acc[fi][fj] = (f32x4){0.f, 0.f, 0.f, 0.f};

#pragma unroll
    for (int kt = 0; kt < 8; ++kt) {
      if (kt < 7)       ISSUE(cur ^ 1, ct, kt + 1);
      else if (it < 32) ISSUE(cur ^ 1, (it + 1 < 32) ? (it + 1) : 0, 0);
      s16x8 af[4], bv[4];
#pragma unroll
      for (int f = 0; f < 4; ++f) {
        af[f] = *(const s16x8*)&Asm[kt][aoff[f]];
        bv[f] = *(const s16x8*)&Bsm[cur][boff[f]];
      }
      __builtin_amdgcn_s_setprio(1);
#pragma unroll
      for (int fi = 0; fi < 4; ++fi)
#pragma unroll
        for (int fj = 0; fj < 4; ++fj)
          acc[fi][fj] = __builtin_amdgcn_mfma_f32_16x16x32_bf16(af[fi], bv[fj], acc[fi][fj], 0, 0, 0);
      __builtin_amdgcn_s_setprio(0);
      __syncthreads();                   // drains loads issued a full stage ago
      cur ^= 1;
    }

    // per-tile epilogue: s = -2*acc (exact). Test via acc >= -thr/2 (exact
    // equivalence); sv computed only when emitting -> bitwise-identical values.
#pragma unroll
    for (int fi = 0; fi < 4; ++fi) {
#pragma unroll
      for (int rg = 0; rg < 4; ++rg) {
        const int rl = fi * 16 + l4 * 4 + rg;
        float amax = acc[fi][0][rg];
#pragma unroll
        for (int fj = 1; fj < 4; ++fj) amax = fmaxf(amax, acc[fi][fj][rg]);
        float smin = -2.0f * amax;               // = min over fj of -2*acc (exact)
        u32 kc = rowKey[rl];                     // stale read => conservative thr
        u32 nk = fkey(smin);
        if (nk < kc) atomicMin(&rowKey[rl], nk);
        if (it >= 1) {
          const float thr = unkey(kc) + mgS[rl];
          const float hthr = -0.5f * thr;        // acc >= hthr  <=>  -2*acc <= thr
          const int nb = ct * 256 + wcol + l15;
#pragma unroll
          for (int fj = 0; fj < 4; ++fj) {
            if (acc[fi][fj][rg] >= hthr) {
              float sv = -2.0f * acc[fi][fj][rg];
              u64 pk = ((u64)__float_as_uint(sv) << 32) | ((u64)(u32)rl << 13)
                     | (u64)(u32)(nb + fj * 16);
              u32 lp = atomicAdd(&lcount, 1u);
              if (lp < LBUF) lbuf[lp] = pk;
              else {                             // overflow backstop -> global list
                u32 p = atomicAdd(counter, 1u);
                if (p < CAP) cands[p] = pk + ((u64)(u32)rowbase << 13);
              }
            }
          }
        }
      }
    }
  }

  // ---- in-block exact resolution ----
  __syncthreads();
  if (tid < 64) {
    float t = unkey(rowKey[tid]) + mgS[tid];
    thrF[tid] = t;
    rowthr[rowbase + tid] = t;                   // for the overflow backstop kernel
  }
  __syncthreads();
  u32 tl = lcount; if (tl > LBUF) tl = LBUF;
  for (u32 i = tid; i < tl; i += 256) {
    u64 c = lbuf[i];
    float s = __uint_as_float((u32)(c >> 32));
    const int rl = (int)((c >> 13) & 63u);
    const int n  = (int)(c & 0x1fffu);
    if (s > thrF[rl]) continue;                  // final-margin filter
    const int m = rowbase + rl;
    const float4* zr = (const float4*)(z + (size_t)m * 256);
    const float4* er = (const float4*)(cb + (size_t)n * 256);
    float acc1 = 0.f;
    for (int j = 0; j < 64; ++j) {   // strict k-ascending sequential fma (sgemm-faithful)
      float4 a = zr[j], b = er[j];
      acc1 = fmaf(a.x, b.x, acc1); acc1 = fmaf(a.y, b.y, acc1);
      acc1 = fmaf(a.z, b.z, acc1); acc1 = fmaf(a.w, b.w, acc1);
    }
    float d = fmaf(-2.f, acc1, Ag[m]);  // = fl(A - 2*acc), single rounding
    u64 key = ((u64)__float_as_uint(d) << 32) | (u64)(u32)n;
    atomicMin(&keys[m], key);
  }
#undef ISSUE
}

// ---------------- overflow backstop: exact eval of spilled candidates ----------------
__global__ __launch_bounds__(256) void vq_exact2(
    const float* __restrict__ z, const float* __restrict__ cb,
    const float* __restrict__ A, const float* __restrict__ rowthr,
    const u64* __restrict__ cands, const u32* __restrict__ counter,
    u64* __restrict__ keys) {
  u32 cnt = *counter; if (cnt > CAP) cnt = CAP;
  for (u32 i = blockIdx.x * 256 + threadIdx.x; i < cnt; i += gridDim.x * 256) {
    u64 c = cands[i];
    float s = __uint_as_float((u32)(c >> 32));
    const int m = (int)((c >> 13) & 0x7fffu);
    const int n = (int)(c & 0x1fffu);
    if (s > rowthr[m]) continue;
    const float4* zr = (const float4*)(z + (size_t)m * 256);
    const float4* er = (const float4*)(cb + (size_t)n * 256);
    float acc = 0.f;
    for (int j = 0; j < 64; ++j) {
      float4 a = zr[j], b = er[j];
      acc = fmaf(a.x, b.x, acc); acc = fmaf(a.y, b.y, acc);
      acc = fmaf(a.z, b.z, acc); acc = fmaf(a.w, b.w, acc);
    }
    float d = fmaf(-2.f, acc, A[m]);
    u64 key = ((u64)__float_as_uint(d) << 32) | (u64)(u32)n;
    atomicMin(&keys[m], key);
  }
}

// ---------------- gather z_q, write z_q_st + indices, loss partials ----------------
__global__ __launch_bounds__(256) void vq_gather_new(
    const float* __restrict__ z, const float* __restrict__ cb,
    const u64* __restrict__ keys, float* __restrict__ idx_out,
    float* __restrict__ zq_out, double* __restrict__ loss_part) {
  __shared__ double lred[4];
  const int tid = threadIdx.x;
  const int rl = tid >> 2, part = tid & 3;
  const int R = blockIdx.x * 64 + rl;
  const int bi = (int)(keys[R] & 0x1fffull);     // clamped: fault insurance
  if (part == 0) idx_out[R] = (float)bi;
  const float4* zr = (const float4*)z + (size_t)R * 64 + part * 16;
  const float4* er = (const float4*)cb + (size_t)bi * 64 + part * 16;
  float4* orow = (float4*)zq_out + (size_t)R * 64 + part * 16;
  double lsum = 0.0;
#pragma unroll
  for (int i = 0; i < 16; ++i) {
    float4 zv = zr[i], ev = er[i];
    float dx = ev.x - zv.x, dy = ev.y - zv.y, dz = ev.z - zv.z, dw = ev.w - zv.w;
    float4 o; o.x = zv.x + dx; o.y = zv.y + dy; o.z = zv.z + dz; o.w = zv.w + dw;
    orow[i] = o;
    lsum += (double)dx * dx + (double)dy * dy + (double)dz * dz + (double)dw * dw;
  }
#pragma unroll
  for (int o = 32; o > 0; o >>= 1) lsum += __shfl_down(lsum, o, 64);
  if ((tid & 63) == 0) lred[tid >> 6] = lsum;
  __syncthreads();
  if (tid == 0) loss_part[blockIdx.x] = lred[0] + lred[1] + lred[2] + lred[3];
}

__global__ void vq_finalize_kernel(const double* __restrict__ loss_part,
                                   float* __restrict__ loss_out) {
  if (threadIdx.x == 0 && blockIdx.x == 0) {
    double s = 0.0;
    for (int b = 0; b < 512; ++b) s += loss_part[b];
    *loss_out = (float)(s / (double)ND_TOTAL * 1.25);
  }
}

// ================= fallback (proven round-2 path, used if ws too small) =================
__global__ __launch_bounds__(256) void vq_argmin_fb(
    const float* __restrict__ z, const float* __restrict__ cb,
    float* __restrict__ idx_out) {
  __shared__ float4 zs[64 * 64];
  const int tid = threadIdx.x;
  const int tc = tid & 15, tr = tid >> 4;
  const int rowbase = blockIdx.x * 64;
  const float4* zg4 = (const float4*)z;
  const float4* cb4 = (const float4*)cb;
  const int swz = (tr & 3) << 1;
#pragma unroll
  for (int i = 0; i < 16; ++i) {
    int idx = i * 256 + tid;
    int row = idx >> 6, dq = idx & 63;
    int col = dq ^ (((row >> 2) & 3) << 1);
    zs[row * 64 + col] = zg4[(size_t)rowbase * 64 + idx];
  }
  __syncthreads();
  float A[4];
#pragma unroll
  for (int r = 0; r < 4; ++r) {
    int row = tr * 4 + r;
    float p = 0.f;
#pragma unroll
    for (int j = 0; j < 4; ++j) {
      int dq = tc + 16 * j;
      float4 v = zs[row * 64 + (dq ^ swz)];
      p = fmaf(v.x, v.x, p); p = fmaf(v.y, v.y, p);
      p = fmaf(v.z, v.z, p); p = fmaf(v.w, v.w, p);
    }
#pragma unroll
    for (int m = 1; m <= 8; m <<= 1) p += __shfl_xor(p, m, 64);
    A[r] = p;
  }
  float b1[4] = {INFINITY, INFINITY, INFINITY, INFINITY};
  int   i1[4] = {0x7fffffff, 0x7fffffff, 0x7fffffff, 0x7fffffff};
  for (int kt = 0; kt < 64; ++kt) {
    const int e0 = kt * 128 + tc * 8;
    const float4* eb = cb4 + (size_t)e0 * 64;
    float acc[4][8];
#pragma unroll
    for (int r = 0; r < 4; ++r)
#pragma unroll
      for (int c = 0; c < 8; ++c) acc[r][c] = 0.f;
#pragma unroll 2
    for (int dq = 0; dq < 64; ++dq) {
      float4 ev[8];
#pragma unroll
      for (int c = 0; c < 8; ++c) ev[c] = eb[c * 64 + dq];
      const int col = dq ^ swz;
      float4 zv[4];
#pragma unroll
      for (int r = 0; r < 4; ++r) zv[r] = zs[(tr * 4 + r) * 64 + col];
#pragma unroll
      for (int r = 0; r < 4; ++r)
#pragma unroll
        for (int c = 0; c < 8; ++c) {
          acc[r][c] = fmaf(zv[r].x, ev[c].x, acc[r][c]);
          acc[r][c] = fmaf(zv[r].y, ev[c].y, acc[r][c]);
          acc[r][c] = fmaf(zv[r].z, ev[c].z, acc[r][c]);
          acc[r][c] = fmaf(zv[r].w, ev[c].w, acc[r][c]);
        }
    }
#pragma unroll
    for (int c = 0; c < 8; ++c)
#pragma unroll
      for (int r = 0; r < 4; ++r) {
        float d = A[r] - 2.0f * acc[r][c];
        if (d < b1[r]) { b1[r] = d; i1[r] = e0 + c; }
      }
  }
  __syncthreads();
  float* rs = (float*)zs;
  int*   ri = (int*)(rs + 64 * 16);
#pragma unroll
  for (int r = 0; r < 4; ++r) {
    rs[(tr * 4 + r) * 16 + tc] = b1[r];
    ri[(tr * 4 + r) * 16 + tc] = i1[r];
  }
  __syncthreads();
  if (tid < 64) {
    float B = INFINITY; int I = 0x7fffffff;
#pragma unroll
    for (int c = 0; c < 16; ++c) {
      float v = rs[tid * 16 + c];
      int  ix = ri[tid * 16 + c];
      if (v < B || (v == B && ix < I)) { B = v; I = ix; }
    }
    idx_out[rowbase + tid] = (float)I;
  }
}

__global__ __launch_bounds__(256) void vq_gather_fb(
    const float* __restrict__ z, const float* __restrict__ cb,
    const float* __restrict__ idx_out, float* __restrict__ zq_out,
    double* __restrict__ loss_part) {
  __shared__ double lred[4];
  const int tid = threadIdx.x;
  const int rl = tid >> 2, part = tid & 3;
  const int R = blockIdx.x * 64 + rl;
  const int bi = (int)idx_out[R];
  const float4* zr = (const float4*)z + (size_t)R * 64 + part * 16;
  const float4* er = (const float4*)cb + (size_t)bi * 64 + part * 16;
  float4* orow = (float4*)zq_out + (size_t)R * 64 + part * 16;
  double lsum = 0.0;
#pragma unroll
  for (int i = 0; i < 16; ++i) {
    float4 zv = zr[i], ev = er[i];
    float dx = ev.x - zv.x, dy = ev.y - zv.y, dz = ev.z - zv.z, dw = ev.w - zv.w;
    float4 o; o.x = zv.x + dx; o.y = zv.y + dy; o.z = zv.z + dz; o.w = zv.w + dw;
    orow[i] = o;
    lsum += (double)dx * dx + (double)dy * dy + (double)dz * dz + (double)dw * dw;
  }
#pragma unroll
  for (int o = 32; o > 0; o >>= 1) lsum += __shfl_down(lsum, o, 64);
  if ((tid & 63) == 0) lred[tid >> 6] = lsum;
  __syncthreads();
  if (tid == 0) loss_part[blockIdx.x] = lred[0] + lred[1] + lred[2] + lred[3];
}

extern "C" void kernel_launch(void* const* d_in, const int* in_sizes, int n_in,
                              void* d_out, int out_size, void* d_ws, size_t ws_size,
                              hipStream_t stream) {
  const float* z  = (const float*)d_in[0];
  const float* cb = (const float*)d_in[1];
  float* out = (float*)d_out;
  float* zq_out   = out;
  float* loss_out = out + ND_TOTAL;
  float* idx_out  = out + ND_TOTAL + 1;

  if (ws_size >= WS_NEEDED) {
    char* ws = (char*)d_ws;
    u32* counter          = (u32*)(ws + WS_COUNTER);
    float* A              = (float*)(ws + WS_A);
    float* marg           = (float*)(ws + WS_MARG);
    float* rowthr         = (float*)(ws + WS_ROWTHR);
    u64* keys             = (u64*)(ws + WS_KEYS);
    u64* cands            = (u64*)(ws + WS_CANDS);
    unsigned short* zh    = (unsigned short*)(ws + WS_ZH);
    unsigned short* eh    = (unsigned short*)(ws + WS_EH);
    double* loss_part     = (double*)(ws + WS_LOSS);

    vq_prep_z<<<NROWS / 4, 256, 0, stream>>>(z, zh, A, marg, keys);
    vq_prep_e<<<KENT / 4, 256, 0, stream>>>(cb, eh, counter);
    vq_fused10<<<NROWS / 64, 256, 0, stream>>>(zh, eh, z, cb, A, marg, rowthr, keys, cands, counter);
    vq_exact2<<<256, 256, 0, stream>>>(z, cb, A, rowthr, cands, counter, keys);
    vq_gather_new<<<NROWS / 64, 256, 0, stream>>>(z, cb, keys, idx_out, zq_out, loss_part);
    vq_finalize_kernel<<<1, 64, 0, stream>>>(loss_part, loss_out);
  } else {
    double* loss_part = (double*)d_ws;   // [512]
    vq_argmin_fb<<<NROWS / 64, 256, 0, stream>>>(z, cb, idx_out);
    vq_gather_fb<<<NROWS / 64, 256, 0, stream>>>(z, cb, idx_out, zq_out, loss_part);
    vq_finalize_kernel<<<1, 64, 0, stream>>>(loss_part, loss_out);
  }
}

// Round 15
// 296.572 us; speedup vs baseline: 1.2351x; 1.2351x over previous
//
#include <hip/hip_runtime.h>

typedef unsigned int u32;
typedef unsigned long long u64;
typedef unsigned short ushort_t;

#define NROWS 32768
#define KENT  8192
#define DDIM  256
#define ND_TOTAL 8388608
#define CAP   1048576u
#define LBUF  1536

// ---- workspace layout (bytes) ----
#define WS_COUNTER   0
#define WS_A         64
#define WS_MARG      131136
#define WS_ROWTHR    262208
#define WS_KEYS      393280
#define WS_CANDS     655424
#define WS_ZH        9044032
#define WS_EH        25821248
#define WS_LOSS      30015552
#define WS_NEEDED    30019648ull

typedef __attribute__((ext_vector_type(8))) short s16x8;
typedef __attribute__((ext_vector_type(4))) float f32x4;

__device__ __forceinline__ unsigned short bf16_rne(float f) {
  u32 u = __float_as_uint(f);
  u32 r = (u + 0x7fffu + ((u >> 16) & 1u)) >> 16;
  return (unsigned short)r;
}

// monotone float<->u32 key; smaller float => smaller key
__device__ __forceinline__ u32 fkey(float s) {
  u32 b = __float_as_uint(s);
  u32 mask = (u32)((int)b >> 31);
  return b ^ (mask | 0x80000000u);
}
__device__ __forceinline__ float unkey(u32 k) {
  u32 b = (k & 0x80000000u) ? (k ^ 0x80000000u) : ~k;
  return __uint_as_float(b);
}
#define KEY_INF 0xFF800000u   // fkey(+inf); NOT 0xFFFFFFFF (that's NaN)

// async global->LDS: 16B/lane, LDS dest = wave-uniform base + lane*16
__device__ __forceinline__ void gll16(const void* g, void* l) {
  __builtin_amdgcn_global_load_lds((const __attribute__((address_space(1))) void*)g,
                                   (__attribute__((address_space(3))) void*)l, 16, 0, 0);
}

// ---------------- prep: z -> bf16, A, margin, init keys ----------------
__global__ __launch_bounds__(256) void vq_prep_z(
    const float* __restrict__ z, unsigned short* __restrict__ zh,
    float* __restrict__ A, float* __restrict__ marg, u64* __restrict__ keys) {
  const int wid = threadIdx.x >> 6, lane = threadIdx.x & 63;
  const int row = blockIdx.x * 4 + wid;
  float4 v = ((const float4*)z)[(size_t)row * 64 + lane];
  ushort4 h;
  h.x = bf16_rne(v.x); h.y = bf16_rne(v.y); h.z = bf16_rne(v.z); h.w = bf16_rne(v.w);
  *(ushort4*)&zh[(size_t)row * 256 + lane * 4] = h;
  double s  = (double)v.x * v.x + (double)v.y * v.y + (double)v.z * v.z + (double)v.w * v.w;
  double s1 = fabs((double)v.x) + fabs((double)v.y) + fabs((double)v.z) + fabs((double)v.w);
#pragma unroll
  for (int m = 1; m <= 32; m <<= 1) { s += __shfl_xor(s, m, 64); s1 += __shfl_xor(s1, m, 64); }
  if (lane == 0) {
    float Af = (float)s;
    u32 bits = __float_as_uint(Af);
    float ulpA = __uint_as_float((bits & 0x7f800000u) - (23u << 23));  // A >= 128 always
    A[row] = Af;
    // marg >= 2*ulpA + 2*E_dot (bf16-conversion bound); proven rounds 3-14
    marg[row] = 4.0f * ulpA + 3.86e-6f * (float)s1 + 4e-6f;
    keys[row] = ~0ull;
  }
}

// ---------------- prep: codebook -> bf16, zero counter ----------------
__global__ __launch_bounds__(256) void vq_prep_e(
    const float* __restrict__ cb, unsigned short* __restrict__ eh,
    u32* __restrict__ counter) {
  if (blockIdx.x == 0 && threadIdx.x == 0) *counter = 0u;
  const int wid = threadIdx.x >> 6, lane = threadIdx.x & 63;
  const int row = blockIdx.x * 4 + wid;
  float4 v = ((const float4*)cb)[(size_t)row * 64 + lane];
  ushort4 h;
  h.x = bf16_rne(v.x); h.y = bf16_rne(v.y); h.z = bf16_rne(v.z); h.w = bf16_rne(v.w);
  *(ushort4*)&eh[(size_t)row * 256 + lane * 4] = h;
}

// ---------------- fused single-sweep GEMM + in-block exact resolution ----------------
// r10 champion structure (512 blocks x 64 rows, 512 thr / 8 waves, 16 waves/CU,
// wave = 16r x 128c, areg[8] in regs) with HALF THE BARRIERS: each stage covers
// K=64 (two 16KB kt-sub-buffers inside a 32KB buffer; 16 MFMA/wave between
// barriers). Evidence r8-r14: per-barrier lockstep overhead is ~fixed
// (~1300-1800cy) regardless of per-stage bytes/waits -> amortize it.
// Tile order [0,1..31,0] (tile-0 warmup, emission at it=32). Candidates ->
// LDS buffer, resolved in-block (bit-faithful sequential fmaf f32); global
// list = overflow backstop.
__global__ __launch_bounds__(512, 4) void vq_fused11(
    const ushort_t* __restrict__ zh, const ushort_t* __restrict__ eh,
    const float* __restrict__ z, const float* __restrict__ cb,
    const float* __restrict__ Ag, const float* __restrict__ marg,
    float* __restrict__ rowthr, u64* __restrict__ keys,
    u64* __restrict__ cands, u32* __restrict__ counter) {
  __shared__ __align__(16) ushort_t Bsm[2][16384];  // 2 x 32KB; each = 2 x 16KB kt-sub-buffers
  __shared__ u32 rowKey[64];
  __shared__ u64 lbuf[LBUF];                        // 12KB
  __shared__ u32 lcount;
  __shared__ float thrF[64];

  const int tid = threadIdx.x, w = tid >> 6, lane = tid & 63;
  const int l15 = lane & 15, l4 = lane >> 4;
  const int wrow = (w >> 1) * 16, wcol = (w & 1) * 128;   // 4 row-groups x 2 col-groups
  const int rowbase = blockIdx.x * 64;

  if (tid < 64) rowKey[tid] = KEY_INF;
  if (tid == 0) lcount = 0u;

  // ---- A fragments in registers (32 VGPR): 16 rows per wave
  s16x8 areg[8];
#pragma unroll
  for (int kt = 0; kt < 8; ++kt)
    areg[kt] = *(const s16x8*)(zh + (size_t)(rowbase + wrow + l15) * 256 + kt * 32 + l4 * 8);
  // per-thread row margins (rows wrow + l4*4 + rg)
  float mg[4];
#pragma unroll
  for (int rg = 0; rg < 4; ++rg)
    mg[rg] = marg[rowbase + wrow + l4 * 4 + rg];

  // ---- B staging (proven formulas): within a 16KB sub-buffer, slot t in
  // [0,1024): entry e=t>>2, stored chunk c=t&3 holds global chunk c^((e>>1)&3).
  // Each wave stages 2 slots per sub-buffer; a stage = 2 sub-buffers (K=64).
  const int t0 = w * 128 + lane, t1 = t0 + 64;
  const int e0 = t0 >> 2, e1 = t1 >> 2;
  const ushort_t* gs0 = eh + (size_t)e0 * 256 + (((t0 & 3) ^ ((e0 >> 1) & 3)) * 8);
  const ushort_t* gs1 = eh + (size_t)e1 * 256 + (((t1 & 3) ^ ((e1 >> 1) & 3)) * 8);

  // issue one K=64 stage (kt pair KTP*2, KTP*2+1) for col-tile CT into buffer BUF
#define ISSUE(BUF, CT, KTP) do {                                          \
    size_t o0_ = (size_t)(CT) * 65536 + (size_t)((KTP) * 2) * 32;         \
    gll16(gs0 + o0_, &Bsm[(BUF)][w * 1024]);                              \
    gll16(gs1 + o0_, &Bsm[(BUF)][w * 1024 + 512]);                        \
    gll16(gs0 + o0_ + 32, &Bsm[(BUF)][8192 + w * 1024]);                  \
    gll16(gs1 + o0_ + 32, &Bsm[(BUF)][8192 + w * 1024 + 512]);            \
  } while (0)

  // swizzled read offsets (ushort index within a 16KB sub-buffer)
  int boff[8];
#pragma unroll
  for (int fj = 0; fj < 8; ++fj) {
    int e = wcol + fj * 16 + l15;
    boff[fj] = e * 32 + (l4 ^ ((e >> 1) & 3)) * 8;
  }

  ISSUE(0, 0, 0);
  __syncthreads();                       // covers LDS init + first stage
  int cur = 0;

#pragma unroll 1
  for (int it = 0; it <= 32; ++it) {
    const int ct = (it < 32) ? it : 0;   // tile 0: warmup at it=0, emission at it=32
    f32x4 acc[8];
#pragma unroll
    for (int fj = 0; fj < 8; ++fj) acc[fj] = (f32x4){0.f, 0.f, 0.f, 0.f};

#pragma unroll
    for (int ktp = 0; ktp < 4; ++ktp) {  // 4 barrier-stages per tile, K=64 each
      if (ktp < 3)      ISSUE(cur ^ 1, ct, ktp + 1);
      else if (it < 32) ISSUE(cur ^ 1, (it + 1 < 32) ? (it + 1) : 0, 0);
      __builtin_amdgcn_s_setprio(1);
#pragma unroll
      for (int h = 0; h < 2; ++h) {
        const int hb = h * 8192;
#pragma unroll
        for (int fj = 0; fj < 8; ++fj) {
          s16x8 bv = *(const s16x8*)&Bsm[cur][hb + boff[fj]];
          acc[fj] = __builtin_amdgcn_mfma_f32_16x16x32_bf16(areg[ktp * 2 + h], bv, acc[fj], 0, 0, 0);
        }
      }
      __builtin_amdgcn_s_setprio(0);
      __syncthreads();                   // drains loads issued at top of this stage
      cur ^= 1;
    }

    // per-tile epilogue: s = -2*acc (exact, identical DAG when tile 0 recomputed)
#pragma unroll
    for (int rg = 0; rg < 4; ++rg) {
      const int rl = wrow + l4 * 4 + rg;
      float sv[8];
#pragma unroll
      for (int fj = 0; fj < 8; ++fj) sv[fj] = -2.0f * acc[fj][rg];
      float smin = sv[0];
#pragma unroll
      for (int fj = 1; fj < 8; ++fj) smin = fminf(smin, sv[fj]);
      u32 kc = rowKey[rl];                     // stale read => conservative thr
      u32 nk = fkey(smin);
      if (nk < kc) atomicMin(&rowKey[rl], nk);
      if (it >= 1) {
        const float thr = unkey(kc) + mg[rg];
        const int nb = ct * 256 + wcol + l15;
#pragma unroll
        for (int fj = 0; fj < 8; ++fj) {
          if (sv[fj] <= thr) {
            u64 pk = ((u64)__float_as_uint(sv[fj]) << 32) | ((u64)(u32)rl << 13)
                   | (u64)(u32)(nb + fj * 16);
            u32 lp = atomicAdd(&lcount, 1u);
            if (lp < LBUF) lbuf[lp] = pk;
            else {                             // overflow backstop -> global list
              u32 p = atomicAdd(counter, 1u);
              if (p < CAP) cands[p] = pk + ((u64)(u32)rowbase << 13);
            }
          }
        }
      }
    }
  }

  // ---- in-block exact resolution ----
  __syncthreads();
  if (tid < 64) {
    float t = unkey(rowKey[tid]) + marg[rowbase + tid];
    thrF[tid] = t;
    rowthr[rowbase + tid] = t;                   // for the overflow backstop kernel
  }
  __syncthreads();
  u32 tl = lcount; if (tl > LBUF) tl = LBUF;
  for (u32 i = tid; i < tl; i += 512) {
    u64 c = lbuf[i];
    float s = __uint_as_float((u32)(c >> 32));
    const int rl = (int)((c >> 13) & 63u);
    const int n  = (int)(c & 0x1fffu);
    if (s > thrF[rl]) continue;                  // final-margin filter
    const int m = rowbase + rl;
    const float4* zr = (const float4*)(z + (size_t)m * 256);
    const float4* er = (const float4*)(cb + (size_t)n * 256);
    float acc1 = 0.f;
    for (int j = 0; j < 64; ++j) {   // strict k-ascending sequential fma (sgemm-faithful)
      float4 a = zr[j], b = er[j];
      acc1 = fmaf(a.x, b.x, acc1); acc1 = fmaf(a.y, b.y, acc1);
      acc1 = fmaf(a.z, b.z, acc1); acc1 = fmaf(a.w, b.w, acc1);
    }
    float d = fmaf(-2.f, acc1, Ag[m]);  // = fl(A - 2*acc), single rounding
    u64 key = ((u64)__float_as_uint(d) << 32) | (u64)(u32)n;
    atomicMin(&keys[m], key);
  }
#undef ISSUE
}

// ---------------- overflow backstop: exact eval of spilled candidates ----------------
__global__ __launch_bounds__(256) void vq_exact2(
    const float* __restrict__ z, const float* __restrict__ cb,
    const float* __restrict__ A, const float* __restrict__ rowthr,
    const u64* __restrict__ cands, const u32* __restrict__ counter,
    u64* __restrict__ keys) {
  u32 cnt = *counter; if (cnt > CAP) cnt = CAP;
  for (u32 i = blockIdx.x * 256 + threadIdx.x; i < cnt; i += gridDim.x * 256) {
    u64 c = cands[i];
    float s = __uint_as_float((u32)(c >> 32));
    const int m = (int)((c >> 13) & 0x7fffu);
    const int n = (int)(c & 0x1fffu);
    if (s > rowthr[m]) continue;
    const float4* zr = (const float4*)(z + (size_t)m * 256);
    const float4* er = (const float4*)(cb + (size_t)n * 256);
    float acc = 0.f;
    for (int j = 0; j < 64; ++j) {
      float4 a = zr[j], b = er[j];
      acc = fmaf(a.x, b.x, acc); acc = fmaf(a.y, b.y, acc);
      acc = fmaf(a.z, b.z, acc); acc = fmaf(a.w, b.w, acc);
    }
    float d = fmaf(-2.f, acc, A[m]);
    u64 key = ((u64)__float_as_uint(d) << 32) | (u64)(u32)n;
    atomicMin(&keys[m], key);
  }
}

// ---------------- gather z_q, write z_q_st + indices, loss partials ----------------
__global__ __launch_bounds__(256) void vq_gather_new(
    const float* __restrict__ z, const float* __restrict__ cb,
    const u64* __restrict__ keys, float* __restrict__ idx_out,
    float* __restrict__ zq_out, double* __restrict__ loss_part) {
  __shared__ double lred[4];
  const int tid = threadIdx.x;
  const int rl = tid >> 2, part = tid & 3;
  const int R = blockIdx.x * 64 + rl;
  const int bi = (int)(keys[R] & 0x1fffull);     // clamped: fault insurance
  if (part == 0) idx_out[R] = (float)bi;
  const float4* zr = (const float4*)z + (size_t)R * 64 + part * 16;
  const float4* er = (const float4*)cb + (size_t)bi * 64 + part * 16;
  float4* orow = (float4*)zq_out + (size_t)R * 64 + part * 16;
  double lsum = 0.0;
#pragma unroll
  for (int i = 0; i < 16; ++i) {
    float4 zv = zr[i], ev = er[i];
    float dx = ev.x - zv.x, dy = ev.y - zv.y, dz = ev.z - zv.z, dw = ev.w - zv.w;
    float4 o; o.x = zv.x + dx; o.y = zv.y + dy; o.z = zv.z + dz; o.w = zv.w + dw;
    orow[i] = o;
    lsum += (double)dx * dx + (double)dy * dy + (double)dz * dz + (double)dw * dw;
  }
#pragma unroll
  for (int o = 32; o > 0; o >>= 1) lsum += __shfl_down(lsum, o, 64);
  if ((tid & 63) == 0) lred[tid >> 6] = lsum;
  __syncthreads();
  if (tid == 0) loss_part[blockIdx.x] = lred[0] + lred[1] + lred[2] + lred[3];
}

__global__ void vq_finalize_kernel(const double* __restrict__ loss_part,
                                   float* __restrict__ loss_out) {
  if (threadIdx.x == 0 && blockIdx.x == 0) {
    double s = 0.0;
    for (int b = 0; b < 512; ++b) s += loss_part[b];
    *loss_out = (float)(s / (double)ND_TOTAL * 1.25);
  }
}

// ================= fallback (proven round-2 path, used if ws too small) =================
__global__ __launch_bounds__(256) void vq_argmin_fb(
    const float* __restrict__ z, const float* __restrict__ cb,
    float* __restrict__ idx_out) {
  __shared__ float4 zs[64 * 64];
  const int tid = threadIdx.x;
  const int tc = tid & 15, tr = tid >> 4;
  const int rowbase = blockIdx.x * 64;
  const float4* zg4 = (const float4*)z;
  const float4* cb4 = (const float4*)cb;
  const int swz = (tr & 3) << 1;
#pragma unroll
  for (int i = 0; i < 16; ++i) {
    int idx = i * 256 + tid;
    int row = idx >> 6, dq = idx & 63;
    int col = dq ^ (((row >> 2) & 3) << 1);
    zs[row * 64 + col] = zg4[(size_t)rowbase * 64 + idx];
  }
  __syncthreads();
  float A[4];
#pragma unroll
  for (int r = 0; r < 4; ++r) {
    int row = tr * 4 + r;
    float p = 0.f;
#pragma unroll
    for (int j = 0; j < 4; ++j) {
      int dq = tc + 16 * j;
      float4 v = zs[row * 64 + (dq ^ swz)];
      p = fmaf(v.x, v.x, p); p = fmaf(v.y, v.y, p);
      p = fmaf(v.z, v.z, p); p = fmaf(v.w, v.w, p);
    }
#pragma unroll
    for (int m = 1; m <= 8; m <<= 1) p += __shfl_xor(p, m, 64);
    A[r] = p;
  }
  float b1[4] = {INFINITY, INFINITY, INFINITY, INFINITY};
  int   i1[4] = {0x7fffffff, 0x7fffffff, 0x7fffffff, 0x7fffffff};
  for (int kt = 0; kt < 64; ++kt) {
    const int e0 = kt * 128 + tc * 8;
    const float4* eb = cb4 + (size_t)e0 * 64;
    float acc[4][8];
#pragma unroll
    for (int r = 0; r < 4; ++r)
#pragma unroll
      for (int c = 0; c < 8; ++c) acc[r][c] = 0.f;
#pragma unroll 2
    for (int dq = 0; dq < 64; ++dq) {
      float4 ev[8];
#pragma unroll
      for (int c = 0; c < 8; ++c) ev[c] = eb[c * 64 + dq];
      const int col = dq ^ swz;
      float4 zv[4];
#pragma unroll
      for (int r = 0; r < 4; ++r) zv[r] = zs[(tr * 4 + r) * 64 + col];
#pragma unroll
      for (int r = 0; r < 4; ++r)
#pragma unroll
        for (int c = 0; c < 8; ++c) {
          acc[r][c] = fmaf(zv[r].x, ev[c].x, acc[r][c]);
          acc[r][c] = fmaf(zv[r].y, ev[c].y, acc[r][c]);
          acc[r][c] = fmaf(zv[r].z, ev[c].z, acc[r][c]);
          acc[r][c] = fmaf(zv[r].w, ev[c].w, acc[r][c]);
        }
    }
#pragma unroll
    for (int c = 0; c < 8; ++c)
#pragma unroll
      for (int r = 0; r < 4; ++r) {
        float d = A[r] - 2.0f * acc[r][c];
        if (d < b1[r]) { b1[r] = d; i1[r] = e0 + c; }
      }
  }
  __syncthreads();
  float* rs = (float*)zs;
  int*   ri = (int*)(rs + 64 * 16);
#pragma unroll
  for (int r = 0; r < 4; ++r) {
    rs[(tr * 4 + r) * 16 + tc] = b1[r];
    ri[(tr * 4 + r) * 16 + tc] = i1[r];
  }
  __syncthreads();
  if (tid < 64) {
    float B = INFINITY; int I = 0x7fffffff;
#pragma unroll
    for (int c = 0; c < 16; ++c) {
      float v = rs[tid * 16 + c];
      int  ix = ri[tid * 16 + c];
      if (v < B || (v == B && ix < I)) { B = v; I = ix; }
    }
    idx_out[rowbase + tid] = (float)I;
  }
}

__global__ __launch_bounds__(256) void vq_gather_fb(
    const float* __restrict__ z, const float* __restrict__ cb,
    const float* __restrict__ idx_out, float* __restrict__ zq_out,
    double* __restrict__ loss_part) {
  __shared__ double lred[4];
  const int tid = threadIdx.x;
  const int rl = tid >> 2, part = tid & 3;
  const int R = blockIdx.x * 64 + rl;
  const int bi = (int)idx_out[R];
  const float4* zr = (const float4*)z + (size_t)R * 64 + part * 16;
  const float4* er = (const float4*)cb + (size_t)bi * 64 + part * 16;
  float4* orow = (float4*)zq_out + (size_t)R * 64 + part * 16;
  double lsum = 0.0;
#pragma unroll
  for (int i = 0; i < 16; ++i) {
    float4 zv = zr[i], ev = er[i];
    float dx = ev.x - zv.x, dy = ev.y - zv.y, dz = ev.z - zv.z, dw = ev.w - zv.w;
    float4 o; o.x = zv.x + dx; o.y = zv.y + dy; o.z = zv.z + dz; o.w = zv.w + dw;
    orow[i] = o;
    lsum += (double)dx * dx + (double)dy * dy + (double)dz * dz + (double)dw * dw;
  }
#pragma unroll
  for (int o = 32; o > 0; o >>= 1) lsum += __shfl_down(lsum, o, 64);
  if ((tid & 63) == 0) lred[tid >> 6] = lsum;
  __syncthreads();
  if (tid == 0) loss_part[blockIdx.x] = lred[0] + lred[1] + lred[2] + lred[3];
}

extern "C" void kernel_launch(void* const* d_in, const int* in_sizes, int n_in,
                              void* d_out, int out_size, void* d_ws, size_t ws_size,
                              hipStream_t stream) {
  const float* z  = (const float*)d_in[0];
  const float* cb = (const float*)d_in[1];
  float* out = (float*)d_out;
  float* zq_out   = out;
  float* loss_out = out + ND_TOTAL;
  float* idx_out  = out + ND_TOTAL + 1;

  if (ws_size >= WS_NEEDED) {
    char* ws = (char*)d_ws;
    u32* counter          = (u32*)(ws + WS_COUNTER);
    float* A              = (float*)(ws + WS_A);
    float* marg           = (float*)(ws + WS_MARG);
    float* rowthr         = (float*)(ws + WS_ROWTHR);
    u64* keys             = (u64*)(ws + WS_KEYS);
    u64* cands            = (u64*)(ws + WS_CANDS);
    unsigned short* zh    = (unsigned short*)(ws + WS_ZH);
    unsigned short* eh    = (unsigned short*)(ws + WS_EH);
    double* loss_part     = (double*)(ws + WS_LOSS);

    vq_prep_z<<<NROWS / 4, 256, 0, stream>>>(z, zh, A, marg, keys);
    vq_prep_e<<<KENT / 4, 256, 0, stream>>>(cb, eh, counter);
    vq_fused11<<<NROWS / 64, 512, 0, stream>>>(zh, eh, z, cb, A, marg, rowthr, keys, cands, counter);
    vq_exact2<<<256, 256, 0, stream>>>(z, cb, A, rowthr, cands, counter, keys);
    vq_gather_new<<<NROWS / 64, 256, 0, stream>>>(z, cb, keys, idx_out, zq_out, loss_part);
    vq_finalize_kernel<<<1, 64, 0, stream>>>(loss_part, loss_out);
  } else {
    double* loss_part = (double*)d_ws;   // [512]
    vq_argmin_fb<<<NROWS / 64, 256, 0, stream>>>(z, cb, idx_out);
    vq_gather_fb<<<NROWS / 64, 256, 0, stream>>>(z, cb, idx_out, zq_out, loss_part);
    vq_finalize_kernel<<<1, 64, 0, stream>>>(loss_part, loss_out);
  }
}